// Round 2
// baseline (1799.436 us; speedup 1.0000x reference)
//
#include <hip/hip_runtime.h>

// snn_layer: out[b,u,t] = (sum_f in[b,f,t] * w[f,u] > 1.0f) ? 1.0f : 0.0f
// B=128 F=512 T=256 U=1024, fp32 in/out. No fp32 MFMA on CDNA4 -> vector FMA.
//
// R1 post-mortem: 4x ds_read_b128 per wave-k = 192 CU-cycles of LDS issue vs
// 128 cycles of FMA -> LDS-issue-bound at 66% VALUBusy. Fix: A-operand (w) is
// broadcast across 16 lanes -> read it from global (L2-resident, coalesced to
// ~256B/wave-k) with a depth-2 register pipeline; only B goes through LDS
// (2x ds_read_b128 per wave-k = 96 CU-cycles < 128 FMA cycles).

#define BB 128
#define FF 512
#define TT 256
#define UU 1024

__global__ __launch_bounds__(256, 4)
void snn_gemm_kernel(const float* __restrict__ in, const float* __restrict__ w,
                     float* __restrict__ out) {
    __shared__ float Bs[16][128];  // B = X tile: Bs[k][n], n = t - t0  (8 KB)

    const int b  = blockIdx.z;
    const int u0 = blockIdx.y * 128;
    const int t0 = blockIdx.x * 128;

    const float* __restrict__ inb  = in  + (size_t)b * FF * TT;
    float* __restrict__       outb = out + (size_t)b * UU * TT;

    const int tid = threadIdx.x;
    const int tx  = tid & 15;   // n-dim (t)
    const int ty  = tid >> 4;   // m-dim (u)

    // B staging: tile = 16x128 floats = 512 float4; 256 threads x 2 float4.
    const int k0 = tid >> 5;          // 0..7
    const int c0 = (tid & 31) * 4;    // 0..124
    const int k1 = k0 + 8;            // 8..15

    float acc[8][8];
#pragma unroll
    for (int i = 0; i < 8; i++)
#pragma unroll
        for (int j = 0; j < 8; j++) acc[i][j] = 0.0f;

    // B: prefetch first K-tile into registers.
    float4 b_r0 = *(const float4*)&inb[k0 * TT + t0 + c0];
    float4 b_r1 = *(const float4*)&inb[k1 * TT + t0 + c0];

    // A: per-thread global pointers (broadcast across the 16 lanes sharing ty).
    const float* __restrict__ wA0 = w + u0 + ty * 4;       // + f*UU
    const float* __restrict__ wA1 = wA0 + 64;

    // A register pipeline, depth 2: even k in Aa, odd k in Ab.
    float4 Aa0 = *(const float4*)&wA0[0 * UU];
    float4 Aa1 = *(const float4*)&wA1[0 * UU];
    float4 Ab0 = *(const float4*)&wA0[1 * UU];
    float4 Ab1 = *(const float4*)&wA1[1 * UU];

    for (int f0 = 0; f0 < FF; f0 += 16) {
        // Commit staged B registers to LDS.
        *(float4*)&Bs[k0][c0] = b_r0;
        *(float4*)&Bs[k1][c0] = b_r1;
        __syncthreads();

        // Prefetch next B K-tile (hidden under the compute below).
        if (f0 + 16 < FF) {
            const int fn = f0 + 16;
            b_r0 = *(const float4*)&inb[(fn + k0) * TT + t0 + c0];
            b_r1 = *(const float4*)&inb[(fn + k1) * TT + t0 + c0];
        }

#pragma unroll
        for (int k = 0; k < 16; k++) {
            // Consume this k's A regs (loaded 2 iterations ago).
            const float4 A0 = (k & 1) ? Ab0 : Aa0;
            const float4 A1 = (k & 1) ? Ab1 : Aa1;

            // Issue prefetch for k+2 into the freed parity buffer.
            int fp = f0 + k + 2;
            if (fp >= FF) fp = 0;  // harmless valid address; values never used
            const size_t off = (size_t)fp * UU;
            if (k & 1) {
                Ab0 = *(const float4*)&wA0[off];
                Ab1 = *(const float4*)&wA1[off];
            } else {
                Aa0 = *(const float4*)&wA0[off];
                Aa1 = *(const float4*)&wA1[off];
            }

            const float4 v0 = *(const float4*)&Bs[k][tx * 4];
            const float4 v1 = *(const float4*)&Bs[k][tx * 4 + 64];
            const float am[8] = {A0.x, A0.y, A0.z, A0.w, A1.x, A1.y, A1.z, A1.w};
            const float bn[8] = {v0.x, v0.y, v0.z, v0.w, v1.x, v1.y, v1.z, v1.w};
#pragma unroll
            for (int i = 0; i < 8; i++)
#pragma unroll
                for (int j = 0; j < 8; j++)
                    acc[i][j] = fmaf(am[i], bn[j], acc[i][j]);
        }
        __syncthreads();
    }

    // Epilogue: heaviside(h - 1) == (h > 1.0f), exact in fp32.
#pragma unroll
    for (int i = 0; i < 8; i++) {
        const int m = (i < 4) ? (ty * 4 + i) : (64 + ty * 4 + i - 4);
        float* __restrict__ orow = outb + (size_t)(u0 + m) * TT + t0;
        float4 o0, o1;
        o0.x = acc[i][0] > 1.0f ? 1.0f : 0.0f;
        o0.y = acc[i][1] > 1.0f ? 1.0f : 0.0f;
        o0.z = acc[i][2] > 1.0f ? 1.0f : 0.0f;
        o0.w = acc[i][3] > 1.0f ? 1.0f : 0.0f;
        o1.x = acc[i][4] > 1.0f ? 1.0f : 0.0f;
        o1.y = acc[i][5] > 1.0f ? 1.0f : 0.0f;
        o1.z = acc[i][6] > 1.0f ? 1.0f : 0.0f;
        o1.w = acc[i][7] > 1.0f ? 1.0f : 0.0f;
        *(float4*)&orow[tx * 4]      = o0;
        *(float4*)&orow[tx * 4 + 64] = o1;
    }
}

extern "C" void kernel_launch(void* const* d_in, const int* in_sizes, int n_in,
                              void* d_out, int out_size, void* d_ws, size_t ws_size,
                              hipStream_t stream) {
    const float* in = (const float*)d_in[0];  // [128,512,256]
    const float* w  = (const float*)d_in[1];  // [512,1024]
    float* out      = (float*)d_out;          // [128,1024,256]

    dim3 grid(TT / 128, UU / 128, BB);  // (2, 8, 128) = 2048 blocks
    snn_gemm_kernel<<<grid, dim3(256), 0, stream>>>(in, w, out);
}

// Round 3
// 1085.105 us; speedup vs baseline: 1.6583x; 1.6583x over previous
//
#include <hip/hip_runtime.h>

// snn_layer: out[b,u,t] = (sum_f in[b,f,t] * w[f,u] > 1.0f) ? 1.0f : 0.0f
// B=128 F=512 T=256 U=1024, fp32. No fp32 MFMA -> vector FMA, floor 219 us.
//
// R1: both operands via LDS -> LDS-port-bound (4x ds_read_b128/wave-k = 192
//     port-cyc vs 128 FMA-cyc -> 66% VALU). R2: A from global per-k ->
//     latency/L2-thrash disaster (FETCH 5x, VALU 15%).
// R3: block = 1 wave, wave owns 32 u-rows. A addresses depend only on
//     blockIdx + loop index -> uniform -> s_load_dwordx16 (scalar cache,
//     zero LDS/VMEM port cost); v_fmac takes the SGPR operand directly.
//     B staged global->LDS via __builtin_amdgcn_global_load_lds (16B, no
//     VGPR roundtrip), double-buffered; the vmcnt drain (inside
//     __syncthreads) happens BEFORE issuing next-tile loads, so it only
//     waits on loads issued a full tile (~2048 FMA-cyc) earlier.
// Per wave-k: 256 FMA SIMD-cyc vs ~24 LDS port-cyc -> FMA-bound (port 37%).

#define FF 512
#define TT 256
#define UU 1024
#define BK 8
#define MW 32   // u-rows per block (per wave)

typedef float floatx16 __attribute__((ext_vector_type(16)));

__global__ __launch_bounds__(64, 3)
void snn_wave_gemm(const float* __restrict__ in, const float* __restrict__ w,
                   float* __restrict__ out) {
    __shared__ float Bs[2][BK][TT];   // 2 x 8 x 256 floats = 16 KB

    const int b    = blockIdx.y;
    const int u0   = blockIdx.x * MW;
    const int lane = threadIdx.x;     // 0..63

    const float* __restrict__ inb = in + (size_t)b * FF * TT;

    float4 acc[MW];
#pragma unroll
    for (int i = 0; i < MW; i++) acc[i] = float4{0.f, 0.f, 0.f, 0.f};

    // Stage tile 0 -> buffer 0 (one 1KB row per instruction: lane L's 16B
    // lands at wave-uniform base + 16*L == Bs[0][r][4L..4L+3]).
#pragma unroll
    for (int r = 0; r < BK; r++) {
        __builtin_amdgcn_global_load_lds(
            (const __attribute__((address_space(1))) void*)(inb + r * TT + lane * 4),
            (__attribute__((address_space(3))) void*)&Bs[0][r][0],
            16, 0, 0);
    }

    for (int f0 = 0; f0 < FF; f0 += BK) {
        const int buf = (f0 / BK) & 1;

        // Drain THIS buffer's loads (issued one full tile ago -> ~free) and
        // order LDS. Issue next tile only AFTER the drain so vmcnt(0) never
        // waits on fresh loads.
        __syncthreads();

        if (f0 + BK < FF) {
#pragma unroll
            for (int r = 0; r < BK; r++) {
                __builtin_amdgcn_global_load_lds(
                    (const __attribute__((address_space(1))) void*)
                        (inb + (f0 + BK + r) * TT + lane * 4),
                    (__attribute__((address_space(3))) void*)&Bs[buf ^ 1][r][0],
                    16, 0, 0);
            }
        }

#pragma unroll
        for (int k = 0; k < BK; k++) {
            const int f = f0 + k;
            // Wave-uniform 64B A-rows -> s_load_dwordx16 x2 (SGPRs).
            const floatx16* __restrict__ pa =
                (const floatx16*)(w + (size_t)f * UU + u0);
            const floatx16 aL = pa[0];   // w[f][u0 .. u0+15]
            const floatx16 aH = pa[1];   // w[f][u0+16 .. u0+31]

            const float4 vb = *(const float4*)&Bs[buf][k][lane * 4];

#pragma unroll
            for (int i = 0; i < 16; i++) {
                acc[i].x = fmaf(aL[i], vb.x, acc[i].x);
                acc[i].y = fmaf(aL[i], vb.y, acc[i].y);
                acc[i].z = fmaf(aL[i], vb.z, acc[i].z);
                acc[i].w = fmaf(aL[i], vb.w, acc[i].w);
            }
#pragma unroll
            for (int i = 0; i < 16; i++) {
                acc[16 + i].x = fmaf(aH[i], vb.x, acc[16 + i].x);
                acc[16 + i].y = fmaf(aH[i], vb.y, acc[16 + i].y);
                acc[16 + i].z = fmaf(aH[i], vb.z, acc[16 + i].z);
                acc[16 + i].w = fmaf(aH[i], vb.w, acc[16 + i].w);
            }
        }
    }

    // Epilogue: heaviside(h - 1) == (h > 1.0f), exact in fp32.
    float* __restrict__ outb = out + ((size_t)b * UU + u0) * TT;
#pragma unroll
    for (int i = 0; i < MW; i++) {
        float4 o;
        o.x = acc[i].x > 1.0f ? 1.0f : 0.0f;
        o.y = acc[i].y > 1.0f ? 1.0f : 0.0f;
        o.z = acc[i].z > 1.0f ? 1.0f : 0.0f;
        o.w = acc[i].w > 1.0f ? 1.0f : 0.0f;
        *(float4*)&outb[(size_t)i * TT + lane * 4] = o;
    }
}

extern "C" void kernel_launch(void* const* d_in, const int* in_sizes, int n_in,
                              void* d_out, int out_size, void* d_ws, size_t ws_size,
                              hipStream_t stream) {
    const float* in = (const float*)d_in[0];  // [128,512,256]
    const float* w  = (const float*)d_in[1];  // [512,1024]
    float* out      = (float*)d_out;          // [128,1024,256]

    // grid.x = u-tiles (32 consecutive blocks share the same b -> their
    // in-rows co-reside in L2 across XCDs), grid.y = batch.
    dim3 grid(UU / MW, 128);  // (32, 128) = 4096 single-wave blocks
    snn_wave_gemm<<<grid, dim3(64), 0, stream>>>(in, w, out);
}

// Round 4
// 648.900 us; speedup vs baseline: 2.7731x; 1.6722x over previous
//
#include <hip/hip_runtime.h>

// snn_layer: out[b,u,t] = (sum_f in[b,f,t] * w[f,u] > 1.0f) ? 1.0f : 0.0f
// B=128 F=512 T=256 U=1024, fp32. No fp32 MFMA -> vector FMA, floor 219 us.
//
// R1 (440us): both operands via LDS -> LDS-port-bound at 66% VALU.
// R2 (1800us): per-k divergent global A -> latency/L2 thrash.
// R3 (1085us): SGPR-A concept, but acc[32]xfloat4 = 128 VGPR demand spilled
//     (VGPR_Count=84, WRITE_SIZE 5x output) and 256-SGPR tile hoist forced
//     per-k lgkmcnt(0) drains with only 1 wave/block -> nothing hid them.
// R4: same SGPR-A idea, shaped to avoid both failure modes:
//     - block = 4 waves split along t (tid == t). All waves share the same
//       32 u-rows -> A address has NO threadIdx term -> provably uniform ->
//       s_load_dwordx16; v_fmac takes the SGPR operand directly.
//     - acc = 32 scalar floats/lane -> ~50 VGPR total -> 8 waves/EU; the
//       unavoidable per-k SMEM lgkmcnt(0) drains are hidden by TLP.
//     - B double-buffered via global_load_lds (no staging VGPRs), drain
//       (inside __syncthreads) BEFORE issuing next tile's DMA.
// Per-CU balance per 64 FMA-cyc: LDS port ~35 cyc (1x ds_read_b32 + DMA
// write share) -> FMA-bound at ~55% port.

#define FF 512
#define TT 256
#define UU 1024
#define BK 8
#define MW 32   // u-rows per block (shared by all 4 waves)

typedef float floatx16 __attribute__((ext_vector_type(16)));

__global__ __launch_bounds__(256, 4)
void snn_gemm_r4(const float* __restrict__ in, const float* __restrict__ w,
                 float* __restrict__ out) {
    __shared__ float Bs[2][BK][TT];   // 2 x 8 x 256 floats = 16 KB

    const int b    = blockIdx.y;
    const int u0   = blockIdx.x * MW;        // uniform
    const int tid  = threadIdx.x;            // == t index, 0..255
    const int wv   = tid >> 6;               // wave id 0..3
    const int lane = tid & 63;

    const float* __restrict__ inb = in + (size_t)b * FF * TT;

    float acc[MW];
#pragma unroll
    for (int i = 0; i < MW; i++) acc[i] = 0.0f;

    // Stage tile 0 -> buffer 0. Wave wv stages rows {2wv, 2wv+1}; lane L's
    // 16B lands at LDS base + 16L -> contiguous 1KB row.
#pragma unroll
    for (int j = 0; j < 2; j++) {
        const int row = 2 * wv + j;
        __builtin_amdgcn_global_load_lds(
            (const __attribute__((address_space(1))) void*)(inb + row * TT + lane * 4),
            (__attribute__((address_space(3))) void*)&Bs[0][row][0],
            16, 0, 0);
    }

    for (int f0 = 0; f0 < FF; f0 += BK) {
        const int buf = (f0 / BK) & 1;

        // Barrier drains last tile's DMA (in flight for a whole tile) and
        // protects buf^1 from overwrite while still being read.
        __syncthreads();

        if (f0 + BK < FF) {
#pragma unroll
            for (int j = 0; j < 2; j++) {
                const int row = 2 * wv + j;
                __builtin_amdgcn_global_load_lds(
                    (const __attribute__((address_space(1))) void*)
                        (inb + (f0 + BK + row) * TT + lane * 4),
                    (__attribute__((address_space(3))) void*)&Bs[buf ^ 1][row][0],
                    16, 0, 0);
            }
        }

#pragma unroll
        for (int k = 0; k < BK; k++) {
            // Wave-uniform 128B A-row slice -> 2x s_load_dwordx16 (SGPRs).
            const floatx16* __restrict__ pa =
                (const floatx16*)(w + (size_t)(f0 + k) * UU + u0);
            const floatx16 aL = pa[0];   // w[f][u0 .. u0+15]
            const floatx16 aH = pa[1];   // w[f][u0+16 .. u0+31]

            const float vb = Bs[buf][k][tid];   // ds_read_b32, 2-way alias (free)

#pragma unroll
            for (int i = 0; i < 16; i++)
                acc[i] = fmaf(aL[i], vb, acc[i]);
#pragma unroll
            for (int i = 0; i < 16; i++)
                acc[16 + i] = fmaf(aH[i], vb, acc[16 + i]);
        }
    }

    // Epilogue: heaviside(h - 1) == (h > 1.0f), exact in fp32.
    // tid-contiguous stores -> coalesced 1KB per block-row.
    float* __restrict__ outb = out + ((size_t)b * UU + u0) * TT + tid;
#pragma unroll
    for (int i = 0; i < MW; i++)
        outb[(size_t)i * TT] = acc[i] > 1.0f ? 1.0f : 0.0f;
}

extern "C" void kernel_launch(void* const* d_in, const int* in_sizes, int n_in,
                              void* d_out, int out_size, void* d_ws, size_t ws_size,
                              hipStream_t stream) {
    const float* in = (const float*)d_in[0];  // [128,512,256]
    const float* w  = (const float*)d_in[1];  // [512,1024]
    float* out      = (float*)d_out;          // [128,1024,256]

    dim3 grid(UU / MW, 128);  // (32, 128) = 4096 blocks, 4 waves each
    snn_gemm_r4<<<grid, dim3(256), 0, stream>>>(in, w, out);
}

// Round 5
// 587.041 us; speedup vs baseline: 3.0653x; 1.1054x over previous
//
#include <hip/hip_runtime.h>

// snn_layer: out[b,u,t] = (sum_f in[b,f,t] * w[f,u] > 1.0f) ? 1.0f : 0.0f
// B=128 F=512 T=256 U=1024, fp32. No fp32 MFMA -> vector FMA, floor 219 us.
//
// R1 (440us): A+B via LDS -> LDS-port-bound, VALU 66%.
// R2 (1800us): divergent per-k global A -> latency/L2 thrash.
// R3 (1085us): SGPR-A + float4, acc spilled (128 VGPR demand).
// R4 (551us): SGPR-A + scalar acc + LDS-B. VALU 48%: s_load and ds_read
//     share lgkmcnt and SMEM completes OUT-OF-ORDER -> every ds_read use
//     forces lgkmcnt(0), draining all prefetched s_loads -> serialized.
// R5: separate the counter domains. NO LDS anywhere:
//     - B: tid==t -> inb[f*TT+tid] is perfectly coalesced; double-buffered
//       global->VGPR tile (vmcnt domain). The tile-boundary vmcnt wait
//       covers loads issued 512 FMA-cyc earlier.
//     - A: wave-uniform w rows -> s_load_dwordx16 x2 per k, now the SOLE
//       lgkmcnt user -> compiler can hoist/batch without forced drains.
//     - no __syncthreads, VGPR ~56 -> 6+ waves/EU of TLP.

#define FF 512
#define TT 256
#define UU 1024
#define BK 8
#define MW 32   // u-rows per block

typedef float floatx16 __attribute__((ext_vector_type(16)));

__global__ __launch_bounds__(256, 6)
void snn_gemm_r5(const float* __restrict__ in, const float* __restrict__ w,
                 float* __restrict__ out) {
    const int b   = blockIdx.y;
    const int u0  = blockIdx.x * MW;   // uniform
    const int tid = threadIdx.x;       // == t, 0..255

    // Per-lane B column pointer (coalesced across each wave).
    const float* __restrict__ inb = in + (size_t)b * FF * TT + tid;

    float acc[MW];
#pragma unroll
    for (int i = 0; i < MW; i++) acc[i] = 0.0f;

    float cur[BK], nxt[BK];
#pragma unroll
    for (int r = 0; r < BK; r++) cur[r] = inb[(size_t)r * TT];

    for (int f0 = 0; f0 < FF; f0 += BK) {
        // Prefetch next B tile (vmcnt domain; consumed one full tile later).
        if (f0 + BK < FF) {
#pragma unroll
            for (int r = 0; r < BK; r++)
                nxt[r] = inb[(size_t)(f0 + BK + r) * TT];
        }

#pragma unroll
        for (int k = 0; k < BK; k++) {
            // Wave-uniform 128B of w -> 2x s_load_dwordx16 (SGPRs; only
            // lgkmcnt users in the kernel).
            const floatx16* __restrict__ pa =
                (const floatx16*)(w + (size_t)(f0 + k) * UU + u0);
            const floatx16 aL = pa[0];   // w[f][u0 .. u0+15]
            const floatx16 aH = pa[1];   // w[f][u0+16 .. u0+31]

            const float vb = cur[k];     // register operand

#pragma unroll
            for (int i = 0; i < 16; i++)
                acc[i] = fmaf(aL[i], vb, acc[i]);
#pragma unroll
            for (int i = 0; i < 16; i++)
                acc[16 + i] = fmaf(aH[i], vb, acc[16 + i]);
        }

#pragma unroll
        for (int r = 0; r < BK; r++) cur[r] = nxt[r];
    }

    // Epilogue: heaviside(h - 1) == (h > 1.0f), exact in fp32. Coalesced.
    float* __restrict__ outb = out + ((size_t)b * UU + u0) * TT + tid;
#pragma unroll
    for (int i = 0; i < MW; i++)
        outb[(size_t)i * TT] = acc[i] > 1.0f ? 1.0f : 0.0f;
}

extern "C" void kernel_launch(void* const* d_in, const int* in_sizes, int n_in,
                              void* d_out, int out_size, void* d_ws, size_t ws_size,
                              hipStream_t stream) {
    const float* in = (const float*)d_in[0];  // [128,512,256]
    const float* w  = (const float*)d_in[1];  // [512,1024]
    float* out      = (float*)d_out;          // [128,1024,256]

    dim3 grid(UU / MW, 128);  // (32, 128) = 4096 blocks, 4 waves each
    snn_gemm_r5<<<grid, dim3(256), 0, stream>>>(in, w, out);
}